// Round 2
// baseline (432.606 us; speedup 1.0000x reference)
//
#include <hip/hip_runtime.h>

#define HH 1024
#define WW 1024
#define NB 8
constexpr int PLANE = HH * WW;
constexpr int TOTAL = NB * PLANE;

#define TILE 62
#define REG 64          // TILE + 2 (rb-region per block)
#define NT 17           // ceil(1024/62)

__device__ __forceinline__ int clampi(int v, int lo, int hi) {
    return v < lo ? lo : (v > hi ? hi : v);
}

__device__ __forceinline__ void cswap(float& a, float& b) {
    float lo = fminf(a, b);
    float hi = fmaxf(a, b);
    a = lo; b = hi;
}

// rank 4 (0-indexed) of 8 = 5th smallest. Pruned Batcher odd-even network, 27 min/max, branch-free.
__device__ __forceinline__ float med8u(float v0, float v1, float v2, float v3,
                                       float v4, float v5, float v6, float v7) {
    cswap(v0, v1); cswap(v2, v3); cswap(v4, v5); cswap(v6, v7);
    cswap(v0, v2); cswap(v1, v3); cswap(v4, v6); cswap(v5, v7);
    cswap(v1, v2); cswap(v5, v6);
    // halves [v0..v3],[v4..v7] now sorted; pruned merge for output index 4:
    float p2 = fminf(v2, v6), p3 = fminf(v3, v7), p4 = fmaxf(v0, v4), p5 = fmaxf(v1, v5);
    return fmaxf(fminf(p3, p5), fmaxf(p2, p4));
}

// rank 2 (0-indexed) of 4 = 2nd largest. 7 ops, branch-free.
__device__ __forceinline__ float med4u(float a, float b, float c, float d) {
    float ab_hi = fmaxf(a, b), ab_lo = fminf(a, b);
    float cd_hi = fmaxf(c, d), cd_lo = fminf(c, d);
    return fmaxf(fminf(ab_hi, cd_hi), fmaxf(ab_lo, cd_lo));
}

// ---------------- demosaick: 4 px/thread, shared 3x6 loads ----------------
__global__ __launch_bounds__(256) void demosaick_kernel(const float* __restrict__ img,
                                                        float* __restrict__ dst) {
    int g = blockIdx.x * blockDim.x + threadIdx.x;
    if (g >= TOTAL / 4) return;
    int pg = g * 4;
    int b = pg / PLANE;
    int p = pg - b * PLANE;
    int y = p >> 10;          // WW = 1024
    int x0 = p & (WW - 1);
    const float* im = img + (size_t)b * PLANE;

    float accR[4] = {0, 0, 0, 0}, accG[4] = {0, 0, 0, 0}, accB[4] = {0, 0, 0, 0};
#pragma unroll
    for (int dy = -1; dy <= 1; ++dy) {
        int cy = clampi(y + dy, 0, HH - 1);
        const float* row = im + cy * WW;
        int py = cy & 1;
        float vr[6], vg[6], vb[6];
#pragma unroll
        for (int j = 0; j < 6; ++j) {
            int cx = clampi(x0 - 1 + j, 0, WW - 1);
            float v = row[cx];
            int px = cx & 1;
            bool isr = (py == 0) && (px == 1);
            bool isb = (py == 1) && (px == 0);
            vr[j] = isr ? v : 0.f;
            vb[j] = isb ? v : 0.f;
            vg[j] = (!isr && !isb) ? v : 0.f;
        }
        int ady = dy < 0 ? -dy : dy;
#pragma unroll
        for (int i = 0; i < 4; ++i) {
#pragma unroll
            for (int dx = -1; dx <= 1; ++dx) {
                int j = i + 1 + dx;
                int adx = dx < 0 ? -dx : dx;
                float wrb = 0.25f * (float)((2 - ady) * (2 - adx));
                accR[i] += wrb * vr[j];
                accB[i] += wrb * vb[j];
                if (ady + adx == 0) accG[i] += vg[j];
                else if (ady + adx == 1) accG[i] += 0.25f * vg[j];
            }
        }
    }
    float* o = dst + (size_t)b * 3 * PLANE + p;
    *reinterpret_cast<float4*>(o) = make_float4(accR[0], accR[1], accR[2], accR[3]);
    *reinterpret_cast<float4*>(o + PLANE) = make_float4(accG[0], accG[1], accG[2], accG[3]);
    *reinterpret_cast<float4*>(o + 2 * PLANE) = make_float4(accB[0], accB[1], accB[2], accB[3]);
}

// ---------------- fused iteration: rb on 64^2 region -> LDS, then g on 62^2 ----------------
__global__ __launch_bounds__(256) void iter_kernel(const float* __restrict__ src,
                                                   float* __restrict__ dst) {
    __shared__ float sG[REG][REG + 1];
    __shared__ float sR[REG][REG + 1];
    __shared__ float sB[REG][REG + 1];

    int bx = blockIdx.x, by = blockIdx.y, bb = blockIdx.z;
    int rx0 = bx * TILE - 1;
    int ry0 = by * TILE - 1;
    const float* Rp = src + (size_t)bb * 3 * PLANE;
    const float* Gp = Rp + PLANE;
    const float* Bp = Rp + 2 * PLANE;
    float* oR = dst + (size_t)bb * 3 * PLANE;
    float* oG = oR + PLANE;
    float* oB = oR + 2 * PLANE;

    int tid = threadIdx.x;
    int tcol = tid & 15;   // 16 groups of 4 cols
    int trow = tid >> 4;   // 16 rows, stride 16

    // ---- Phase 1: Rn = med8(R-G)+G, Bn = med8(B-G)+G on the full 64x64 region ----
    for (int rc = 0; rc < 4; ++rc) {
        int rr = trow + rc * 16;
        int gy = ry0 + rr;
        int yc = clampi(gy, 0, HH - 1);
        int ym = clampi(yc - 1, 0, HH - 1);
        int yp = clampi(yc + 1, 0, HH - 1);
        int gx0 = rx0 + 4 * tcol;

        int cx[6];
#pragma unroll
        for (int j = 0; j < 6; ++j) cx[j] = clampi(gx0 - 1 + j, 0, WW - 1);

        float dR[3][6], dB[3][6], gc[4];
        const int rows[3] = {ym, yc, yp};
#pragma unroll
        for (int rr2 = 0; rr2 < 3; ++rr2) {
            const float* Rrow = Rp + rows[rr2] * WW;
            const float* Grow = Gp + rows[rr2] * WW;
            const float* Brow = Bp + rows[rr2] * WW;
#pragma unroll
            for (int j = 0; j < 6; ++j) {
                float rv = Rrow[cx[j]];
                float gv = Grow[cx[j]];
                float bv = Brow[cx[j]];
                dR[rr2][j] = rv - gv;
                dB[rr2][j] = bv - gv;
                if (rr2 == 1 && j >= 1 && j <= 4) gc[j - 1] = gv;
            }
        }
#pragma unroll
        for (int i = 0; i < 4; ++i) {
            float mR = med8u(dR[0][i], dR[0][i + 1], dR[0][i + 2],
                             dR[1][i], dR[1][i + 2],
                             dR[2][i], dR[2][i + 1], dR[2][i + 2]);
            float mB = med8u(dB[0][i], dB[0][i + 1], dB[0][i + 2],
                             dB[1][i], dB[1][i + 2],
                             dB[2][i], dB[2][i + 1], dB[2][i + 2]);
            float Rn = mR + gc[i];
            float Bn = mB + gc[i];
            int c = 4 * tcol + i;
            sR[rr][c] = Rn;
            sB[rr][c] = Bn;
            sG[rr][c] = gc[i];
            int gx = gx0 + i;
            if (rr >= 1 && rr <= TILE && c >= 1 && c <= TILE && gy < HH && gx < WW) {
                oR[gy * WW + gx] = Rn;
                oB[gy * WW + gx] = Bn;
            }
        }
    }

    __syncthreads();

    // ---- Phase 2: Gn = 0.5*(med4(G-Rn) + med4(G-Bn) + Rn + Bn) on the 62x62 tile ----
    for (int rc = 0; rc < 4; ++rc) {
        int rr = trow + rc * 16;
        if (rr < 1 || rr > TILE) continue;
        int gy = ry0 + rr;
        if (gy >= HH) continue;
        int ur = clampi(gy - 1, 0, HH - 1) - ry0;
        int dr = clampi(gy + 1, 0, HH - 1) - ry0;
        int gx0 = rx0 + 4 * tcol;
#pragma unroll
        for (int i = 0; i < 4; ++i) {
            int c = 4 * tcol + i;
            if (c < 1 || c > TILE) continue;
            int gx = gx0 + i;
            if (gx >= WW) continue;
            int lc = clampi(gx - 1, 0, WW - 1) - rx0;
            int rcx = clampi(gx + 1, 0, WW - 1) - rx0;

            float rn_c = sR[rr][c], bn_c = sB[rr][c];
            float mR = med4u(sG[ur][c] - sR[ur][c],
                             sG[rr][lc] - sR[rr][lc],
                             sG[rr][rcx] - sR[rr][rcx],
                             sG[dr][c] - sR[dr][c]);
            float mB = med4u(sG[ur][c] - sB[ur][c],
                             sG[rr][lc] - sB[rr][lc],
                             sG[rr][rcx] - sB[rr][rcx],
                             sG[dr][c] - sB[dr][c]);
            oG[gy * WW + gx] = 0.5f * (mR + mB + rn_c + bn_c);
        }
    }
}

extern "C" void kernel_launch(void* const* d_in, const int* in_sizes, int n_in,
                              void* d_out, int out_size, void* d_ws, size_t ws_size,
                              hipStream_t stream) {
    const float* img = (const float*)d_in[0];
    float* out = (float*)d_out;
    float* ws = (float*)d_ws;

    dim3 dblock(256);
    dim3 dgrid((TOTAL / 4 + 255) / 256);
    demosaick_kernel<<<dgrid, dblock, 0, stream>>>(img, ws);

    dim3 iblock(256);
    dim3 igrid(NT, NT, NB);
    // demosaick -> ws ; iter1 ws->out ; iter2 out->ws ; iter3 ws->out
    iter_kernel<<<igrid, iblock, 0, stream>>>(ws, out);
    iter_kernel<<<igrid, iblock, 0, stream>>>(out, ws);
    iter_kernel<<<igrid, iblock, 0, stream>>>(ws, out);
}

// Round 3
// 338.178 us; speedup vs baseline: 1.2792x; 1.2792x over previous
//
#include <hip/hip_runtime.h>

#define HH 1024
#define WW 1024
#define NB 8
constexpr int PLANE = HH * WW;
constexpr int TOTAL = NB * PLANE;

#define TILE 62
#define REG 64          // TILE + 2 (rb-region per block)
#define NT 17           // ceil(1024/62)

__device__ __forceinline__ int clampi(int v, int lo, int hi) {
    return v < lo ? lo : (v > hi ? hi : v);
}

__device__ __forceinline__ void cswap(float& a, float& b) {
    float lo = fminf(a, b);
    float hi = fmaxf(a, b);
    a = lo; b = hi;
}

// rank 4 (0-indexed) of 8 = 5th smallest. Pruned Batcher network, branch-free.
__device__ __forceinline__ float med8u(float v0, float v1, float v2, float v3,
                                       float v4, float v5, float v6, float v7) {
    cswap(v0, v1); cswap(v2, v3); cswap(v4, v5); cswap(v6, v7);
    cswap(v0, v2); cswap(v1, v3); cswap(v4, v6); cswap(v5, v7);
    cswap(v1, v2); cswap(v5, v6);
    float p2 = fminf(v2, v6), p3 = fminf(v3, v7), p4 = fmaxf(v0, v4), p5 = fmaxf(v1, v5);
    return fmaxf(fminf(p3, p5), fmaxf(p2, p4));
}

// rank 2 (0-indexed) of 4 = 2nd largest. 7 ops, branch-free.
__device__ __forceinline__ float med4u(float a, float b, float c, float d) {
    float ab_hi = fmaxf(a, b), ab_lo = fminf(a, b);
    float cd_hi = fmaxf(c, d), cd_lo = fminf(c, d);
    return fmaxf(fminf(ab_hi, cd_hi), fmaxf(ab_lo, cd_lo));
}

// load 8 consecutive floats at 16B-aligned base, return 6-float window at base+sm.
// sm is BLOCK-UNIFORM (0 or 2) -> scalar branch, no dynamic indexing.
__device__ __forceinline__ void load_win6(const float* __restrict__ row, int base, int sm,
                                          float w[6]) {
    float4 a = *reinterpret_cast<const float4*>(row + base);
    float4 b = *reinterpret_cast<const float4*>(row + base + 4);
    if (sm == 0) {
        w[0] = a.x; w[1] = a.y; w[2] = a.z; w[3] = a.w; w[4] = b.x; w[5] = b.y;
    } else {
        w[0] = a.z; w[1] = a.w; w[2] = b.x; w[3] = b.y; w[4] = b.z; w[5] = b.w;
    }
}

// 4-float window starting at gx0 (block-uniform misalignment).
__device__ __forceinline__ void load_win4(const float* __restrict__ row, int gx0, float w[4]) {
    int base = gx0 & ~3;
    int off = gx0 & 3;
    float4 a = *reinterpret_cast<const float4*>(row + base);
    float4 b = *reinterpret_cast<const float4*>(row + base + 4);
    if (off == 0)      { w[0] = a.x; w[1] = a.y; w[2] = a.z; w[3] = a.w; }
    else if (off == 1) { w[0] = a.y; w[1] = a.z; w[2] = a.w; w[3] = b.x; }
    else if (off == 2) { w[0] = a.z; w[1] = a.w; w[2] = b.x; w[3] = b.y; }
    else               { w[0] = a.w; w[1] = b.x; w[2] = b.y; w[3] = b.z; }
}

// ---------------- demosaick: 4 px/thread, shared 3x6 loads ----------------
__global__ __launch_bounds__(256) void demosaick_kernel(const float* __restrict__ img,
                                                        float* __restrict__ dst) {
    int g = blockIdx.x * blockDim.x + threadIdx.x;
    if (g >= TOTAL / 4) return;
    int pg = g * 4;
    int b = pg / PLANE;
    int p = pg - b * PLANE;
    int y = p >> 10;          // WW = 1024
    int x0 = p & (WW - 1);
    const float* im = img + (size_t)b * PLANE;

    float accR[4] = {0, 0, 0, 0}, accG[4] = {0, 0, 0, 0}, accB[4] = {0, 0, 0, 0};
#pragma unroll
    for (int dy = -1; dy <= 1; ++dy) {
        int cy = clampi(y + dy, 0, HH - 1);
        const float* row = im + cy * WW;
        int py = cy & 1;
        float vr[6], vg[6], vb[6];
#pragma unroll
        for (int j = 0; j < 6; ++j) {
            int cx = clampi(x0 - 1 + j, 0, WW - 1);
            float v = row[cx];
            int px = cx & 1;
            bool isr = (py == 0) && (px == 1);
            bool isb = (py == 1) && (px == 0);
            vr[j] = isr ? v : 0.f;
            vb[j] = isb ? v : 0.f;
            vg[j] = (!isr && !isb) ? v : 0.f;
        }
        int ady = dy < 0 ? -dy : dy;
#pragma unroll
        for (int i = 0; i < 4; ++i) {
#pragma unroll
            for (int dx = -1; dx <= 1; ++dx) {
                int j = i + 1 + dx;
                int adx = dx < 0 ? -dx : dx;
                float wrb = 0.25f * (float)((2 - ady) * (2 - adx));
                accR[i] += wrb * vr[j];
                accB[i] += wrb * vb[j];
                if (ady + adx == 0) accG[i] += vg[j];
                else if (ady + adx == 1) accG[i] += 0.25f * vg[j];
            }
        }
    }
    float* o = dst + (size_t)b * 3 * PLANE + p;
    *reinterpret_cast<float4*>(o) = make_float4(accR[0], accR[1], accR[2], accR[3]);
    *reinterpret_cast<float4*>(o + PLANE) = make_float4(accG[0], accG[1], accG[2], accG[3]);
    *reinterpret_cast<float4*>(o + 2 * PLANE) = make_float4(accB[0], accB[1], accB[2], accB[3]);
}

// ---------------- fused iteration: rb on 64^2 region -> LDS(R,B), then g on 62^2 ----------------
__global__ __launch_bounds__(256, 4) void iter_kernel(const float* __restrict__ src,
                                                      float* __restrict__ dst) {
    __shared__ float sR[REG][REG + 1];
    __shared__ float sB[REG][REG + 1];

    int bx = blockIdx.x, by = blockIdx.y, bb = blockIdx.z;
    int rx0 = bx * TILE - 1;
    int ry0 = by * TILE - 1;
    const float* Rp = src + (size_t)bb * 3 * PLANE;
    const float* Gp = Rp + PLANE;
    const float* Bp = Rp + 2 * PLANE;
    float* oR = dst + (size_t)bb * 3 * PLANE;
    float* oG = oR + PLANE;
    float* oB = oR + 2 * PLANE;

    int tid = threadIdx.x;
    int tcol = tid & 15;   // 16 groups of 4 cols
    int trow = tid >> 4;   // 16 rows, stride 16
    bool interior = (bx >= 1) && (bx <= 15) && (by >= 1) && (by <= 15);

    // ---- Phase 1: Rn = med8(R-G)+G, Bn = med8(B-G)+G on the 64x64 region ----
    if (interior) {
        for (int rc = 0; rc < 4; ++rc) {
            int rr = trow + rc * 16;
            int gy = ry0 + rr;
            int gx0 = rx0 + 4 * tcol;
            int s = gx0 - 1;
            int base = s & ~3;
            int sm = s & 3;        // 0 or 2, block-uniform
            float dR[3][6], dB[3][6], gcen[6];
#pragma unroll
            for (int r = 0; r < 3; ++r) {
                int yy = gy - 1 + r;
                const float* Rr = Rp + yy * WW;
                const float* Gr = Gp + yy * WW;
                const float* Br = Bp + yy * WW;
                float wR[6], wG[6], wB[6];
                load_win6(Rr, base, sm, wR);
                load_win6(Gr, base, sm, wG);
                load_win6(Br, base, sm, wB);
#pragma unroll
                for (int j = 0; j < 6; ++j) {
                    dR[r][j] = wR[j] - wG[j];
                    dB[r][j] = wB[j] - wG[j];
                }
                if (r == 1) {
#pragma unroll
                    for (int j = 0; j < 6; ++j) gcen[j] = wG[j];
                }
            }
#pragma unroll
            for (int i = 0; i < 4; ++i) {
                float mR = med8u(dR[0][i], dR[0][i + 1], dR[0][i + 2],
                                 dR[1][i], dR[1][i + 2],
                                 dR[2][i], dR[2][i + 1], dR[2][i + 2]);
                float mB = med8u(dB[0][i], dB[0][i + 1], dB[0][i + 2],
                                 dB[1][i], dB[1][i + 2],
                                 dB[2][i], dB[2][i + 1], dB[2][i + 2]);
                float Rn = mR + gcen[i + 1];
                float Bn = mB + gcen[i + 1];
                int c = 4 * tcol + i;
                sR[rr][c] = Rn;
                sB[rr][c] = Bn;
                if (rr >= 1 && rr <= TILE && c >= 1 && c <= TILE) {
                    oR[gy * WW + gx0 + i] = Rn;
                    oB[gy * WW + gx0 + i] = Bn;
                }
            }
        }
    } else {
        for (int rc = 0; rc < 4; ++rc) {
            int rr = trow + rc * 16;
            int gy = ry0 + rr;
            int yc = clampi(gy, 0, HH - 1);
            int ym = clampi(yc - 1, 0, HH - 1);
            int yp = clampi(yc + 1, 0, HH - 1);
            int gx0 = rx0 + 4 * tcol;

            int cx[6];
#pragma unroll
            for (int j = 0; j < 6; ++j) cx[j] = clampi(gx0 - 1 + j, 0, WW - 1);

            float dR[3][6], dB[3][6], gc[4];
            const int rows[3] = {ym, yc, yp};
#pragma unroll
            for (int r = 0; r < 3; ++r) {
                const float* Rrow = Rp + rows[r] * WW;
                const float* Grow = Gp + rows[r] * WW;
                const float* Brow = Bp + rows[r] * WW;
#pragma unroll
                for (int j = 0; j < 6; ++j) {
                    float rv = Rrow[cx[j]];
                    float gv = Grow[cx[j]];
                    float bv = Brow[cx[j]];
                    dR[r][j] = rv - gv;
                    dB[r][j] = bv - gv;
                    if (r == 1 && j >= 1 && j <= 4) gc[j - 1] = gv;
                }
            }
#pragma unroll
            for (int i = 0; i < 4; ++i) {
                float mR = med8u(dR[0][i], dR[0][i + 1], dR[0][i + 2],
                                 dR[1][i], dR[1][i + 2],
                                 dR[2][i], dR[2][i + 1], dR[2][i + 2]);
                float mB = med8u(dB[0][i], dB[0][i + 1], dB[0][i + 2],
                                 dB[1][i], dB[1][i + 2],
                                 dB[2][i], dB[2][i + 1], dB[2][i + 2]);
                float Rn = mR + gc[i];
                float Bn = mB + gc[i];
                int c = 4 * tcol + i;
                sR[rr][c] = Rn;
                sB[rr][c] = Bn;
                int gx = gx0 + i;
                if (rr >= 1 && rr <= TILE && c >= 1 && c <= TILE && gy < HH && gx < WW) {
                    oR[gy * WW + gx] = Rn;
                    oB[gy * WW + gx] = Bn;
                }
            }
        }
    }

    __syncthreads();

    // ---- Phase 2: Gn = 0.5*(med4(G-Rn) + med4(G-Bn) + Rn + Bn) on the 62x62 tile ----
    if (interior) {
        for (int rc = 0; rc < 4; ++rc) {
            int rr = trow + rc * 16;
            if (rr < 1 || rr > TILE) continue;
            int gy = ry0 + rr;
            int gx0 = rx0 + 4 * tcol;
            float gU[4], gD[4], gC[6];
            load_win4(Gp + (gy - 1) * WW, gx0, gU);
            load_win4(Gp + (gy + 1) * WW, gx0, gD);
            {
                int s2 = gx0 - 1;
                load_win6(Gp + gy * WW, s2 & ~3, s2 & 3, gC);
            }
#pragma unroll
            for (int i = 0; i < 4; ++i) {
                int c = 4 * tcol + i;
                if (c < 1 || c > TILE) continue;
                float rn_c = sR[rr][c], bn_c = sB[rr][c];
                float mR = med4u(gU[i] - sR[rr - 1][c], gC[i] - sR[rr][c - 1],
                                 gC[i + 2] - sR[rr][c + 1], gD[i] - sR[rr + 1][c]);
                float mB = med4u(gU[i] - sB[rr - 1][c], gC[i] - sB[rr][c - 1],
                                 gC[i + 2] - sB[rr][c + 1], gD[i] - sB[rr + 1][c]);
                oG[gy * WW + gx0 + i] = 0.5f * (mR + mB + rn_c + bn_c);
            }
        }
    } else {
        for (int rc = 0; rc < 4; ++rc) {
            int rr = trow + rc * 16;
            if (rr < 1 || rr > TILE) continue;
            int gy = ry0 + rr;
            if (gy >= HH) continue;
            int ur = clampi(gy - 1, 0, HH - 1) - ry0;
            int dr = clampi(gy + 1, 0, HH - 1) - ry0;
            int gx0 = rx0 + 4 * tcol;
#pragma unroll
            for (int i = 0; i < 4; ++i) {
                int c = 4 * tcol + i;
                if (c < 1 || c > TILE) continue;
                int gx = gx0 + i;
                if (gx >= WW) continue;
                int lc = clampi(gx - 1, 0, WW - 1) - rx0;
                int rcx = clampi(gx + 1, 0, WW - 1) - rx0;
                float gu = Gp[clampi(gy - 1, 0, HH - 1) * WW + gx];
                float gd = Gp[clampi(gy + 1, 0, HH - 1) * WW + gx];
                float gl = Gp[gy * WW + clampi(gx - 1, 0, WW - 1)];
                float gr = Gp[gy * WW + clampi(gx + 1, 0, WW - 1)];
                float rn_c = sR[rr][c], bn_c = sB[rr][c];
                float mR = med4u(gu - sR[ur][c], gl - sR[rr][lc],
                                 gr - sR[rr][rcx], gd - sR[dr][c]);
                float mB = med4u(gu - sB[ur][c], gl - sB[rr][lc],
                                 gr - sB[rr][rcx], gd - sB[dr][c]);
                oG[gy * WW + gx] = 0.5f * (mR + mB + rn_c + bn_c);
            }
        }
    }
}

extern "C" void kernel_launch(void* const* d_in, const int* in_sizes, int n_in,
                              void* d_out, int out_size, void* d_ws, size_t ws_size,
                              hipStream_t stream) {
    const float* img = (const float*)d_in[0];
    float* out = (float*)d_out;
    float* ws = (float*)d_ws;

    dim3 dblock(256);
    dim3 dgrid((TOTAL / 4 + 255) / 256);
    demosaick_kernel<<<dgrid, dblock, 0, stream>>>(img, ws);

    dim3 iblock(256);
    dim3 igrid(NT, NT, NB);
    // demosaick -> ws ; iter1 ws->out ; iter2 out->ws ; iter3 ws->out
    iter_kernel<<<igrid, iblock, 0, stream>>>(ws, out);
    iter_kernel<<<igrid, iblock, 0, stream>>>(out, ws);
    iter_kernel<<<igrid, iblock, 0, stream>>>(ws, out);
}

// Round 4
// 228.901 us; speedup vs baseline: 1.8899x; 1.4774x over previous
//
#include <hip/hip_runtime.h>

#define HH 1024
#define WW 1024
#define NB 8
constexpr int PLANE = HH * WW;

#define O   32   // output tile
#define R1  34   // phase-1 region (output + 1 halo)
#define R2  36   // staged diff region (output + 2 halo)
#define RD  38   // raw-input region (fused kernel, output + 3 halo)
#define S2  37   // stride of staged planes
#define SD  39   // stride of raw-input plane
#define NTX 32   // 1024 / O

__device__ __forceinline__ int clampi(int v, int lo, int hi) {
    return v < lo ? lo : (v > hi ? hi : v);
}

__device__ __forceinline__ void cswap(float& a, float& b) {
    float lo = fminf(a, b), hi = fmaxf(a, b);
    a = lo; b = hi;
}

// rank 4 (0-indexed) of 8 = 5th smallest. Pruned Batcher network, branch-free.
__device__ __forceinline__ float med8u(float v0, float v1, float v2, float v3,
                                       float v4, float v5, float v6, float v7) {
    cswap(v0, v1); cswap(v2, v3); cswap(v4, v5); cswap(v6, v7);
    cswap(v0, v2); cswap(v1, v3); cswap(v4, v6); cswap(v5, v7);
    cswap(v1, v2); cswap(v5, v6);
    float p2 = fminf(v2, v6), p3 = fminf(v3, v7), p4 = fmaxf(v0, v4), p5 = fmaxf(v1, v5);
    return fmaxf(fminf(p3, p5), fmaxf(p2, p4));
}

// rank 2 (0-indexed) of 4 = 2nd largest. 7 ops, branch-free.
__device__ __forceinline__ float med4u(float a, float b, float c, float d) {
    float ab_hi = fmaxf(a, b), ab_lo = fminf(a, b);
    float cd_hi = fmaxf(c, d), cd_lo = fminf(c, d);
    return fmaxf(fminf(ab_hi, cd_hi), fmaxf(ab_lo, cd_lo));
}

__device__ __forceinline__ void demo_acc(float v, int pyn, int pxn, int ady, int adx,
                                         float& accR, float& accG, float& accB) {
    bool isr = (pyn == 0) && (pxn == 1);
    bool isb = (pyn == 1) && (pxn == 0);
    float wrb = 0.25f * (float)((2 - ady) * (2 - adx));
    int man = ady + adx;
    float wg = (man == 0) ? 1.0f : ((man == 1) ? 0.25f : 0.0f);
    accR += isr ? wrb * v : 0.0f;
    accB += isb ? wrb * v : 0.0f;
    accG += (!isr && !isb) ? wg * v : 0.0f;
}

// phase 1: uR = -med8(dR nbrs), uB = -med8(dB nbrs) on the 34x34 inner region
__device__ __forceinline__ void phase1(const float* __restrict__ sdR,
                                       const float* __restrict__ sdB,
                                       float* __restrict__ uR, float* __restrict__ uB,
                                       int tid, bool interior, int y0, int x0) {
    if (interior) {
        for (int idx = tid; idx < R1 * R1; idx += 256) {
            int r = 1 + idx / R1, c = 1 + (idx - (idx / R1) * R1);
            int q = r * S2 + c;
            float mR = med8u(sdR[q - S2 - 1], sdR[q - S2], sdR[q - S2 + 1],
                             sdR[q - 1],                   sdR[q + 1],
                             sdR[q + S2 - 1], sdR[q + S2], sdR[q + S2 + 1]);
            float mB = med8u(sdB[q - S2 - 1], sdB[q - S2], sdB[q - S2 + 1],
                             sdB[q - 1],                   sdB[q + 1],
                             sdB[q + S2 - 1], sdB[q + S2], sdB[q + S2 + 1]);
            uR[q] = -mR;
            uB[q] = -mB;
        }
    } else {
        for (int idx = tid; idx < R1 * R1; idx += 256) {
            int r = 1 + idx / R1, c = 1 + (idx - (idx / R1) * R1);
            int gy = clampi(y0 + r, 0, HH - 1), gx = clampi(x0 + c, 0, WW - 1);
            int rm = clampi(gy - 1, 0, HH - 1) - y0, rp = clampi(gy + 1, 0, HH - 1) - y0;
            int cm = clampi(gx - 1, 0, WW - 1) - x0, cp = clampi(gx + 1, 0, WW - 1) - x0;
            float mR = med8u(sdR[rm * S2 + cm], sdR[rm * S2 + c], sdR[rm * S2 + cp],
                             sdR[r * S2 + cm],                    sdR[r * S2 + cp],
                             sdR[rp * S2 + cm], sdR[rp * S2 + c], sdR[rp * S2 + cp]);
            float mB = med8u(sdB[rm * S2 + cm], sdB[rm * S2 + c], sdB[rm * S2 + cp],
                             sdB[r * S2 + cm],                    sdB[r * S2 + cp],
                             sdB[rp * S2 + cm], sdB[rp * S2 + c], sdB[rp * S2 + cp]);
            uR[r * S2 + c] = -mR;
            uB[r * S2 + c] = -mB;
        }
    }
}

// phase 2: Rn = G-uR, Bn = G-uB, Gn = 0.5*(med4(uR)+med4(uB)+Rn+Bn) on 32x32; write out
__device__ __forceinline__ void phase2(const float* __restrict__ sG,
                                       const float* __restrict__ uR,
                                       const float* __restrict__ uB,
                                       float* __restrict__ oR, float* __restrict__ oG,
                                       float* __restrict__ oB,
                                       int tid, bool interior, int y0, int x0) {
    if (interior) {
#pragma unroll
        for (int k = 0; k < 4; ++k) {
            int idx = tid + k * 256;
            int r = 2 + (idx >> 5), c = 2 + (idx & 31);
            int q = r * S2 + c;
            float uRc = uR[q], uBc = uB[q], Gc = sG[q];
            float mR = med4u(uR[q - S2], uR[q - 1], uR[q + 1], uR[q + S2]);
            float mB = med4u(uB[q - S2], uB[q - 1], uB[q + 1], uB[q + S2]);
            float Rn = Gc - uRc, Bn = Gc - uBc;
            float Gn = 0.5f * (mR + mB + Rn + Bn);
            int go = (y0 + r) * WW + (x0 + c);
            oR[go] = Rn;
            oB[go] = Bn;
            oG[go] = Gn;
        }
    } else {
#pragma unroll
        for (int k = 0; k < 4; ++k) {
            int idx = tid + k * 256;
            int r = 2 + (idx >> 5), c = 2 + (idx & 31);
            int gy = y0 + r, gx = x0 + c;  // always in range: tiles cover image exactly
            int rm = clampi(gy - 1, 0, HH - 1) - y0, rp = clampi(gy + 1, 0, HH - 1) - y0;
            int cm = clampi(gx - 1, 0, WW - 1) - x0, cp = clampi(gx + 1, 0, WW - 1) - x0;
            int q = r * S2 + c;
            float uRc = uR[q], uBc = uB[q], Gc = sG[q];
            float mR = med4u(uR[rm * S2 + c], uR[r * S2 + cm], uR[r * S2 + cp], uR[rp * S2 + c]);
            float mB = med4u(uB[rm * S2 + c], uB[r * S2 + cm], uB[r * S2 + cp], uB[rp * S2 + c]);
            float Rn = Gc - uRc, Bn = Gc - uBc;
            float Gn = 0.5f * (mR + mB + Rn + Bn);
            int go = gy * WW + gx;
            oR[go] = Rn;
            oB[go] = Bn;
            oG[go] = Gn;
        }
    }
}

// ---------------- kernel A: demosaick (in LDS) + iteration 1 ----------------
__global__ __launch_bounds__(256) void demo_iter1_kernel(const float* __restrict__ img,
                                                         float* __restrict__ dst) {
    __shared__ float smem[RD * SD + 4 * R2 * S2];
    float* sI  = smem;                 // raw input region; aliased by uR after demosaick
    float* sdR = smem + RD * SD;
    float* sdB = sdR + R2 * S2;
    float* sG  = sdB + R2 * S2;
    float* uB  = sG + R2 * S2;
    float* uR  = sI;                   // RD*SD = 1482 >= R2*S2 = 1332

    int bx = blockIdx.x, by = blockIdx.y, bb = blockIdx.z;
    int x0 = bx * O - 2, y0 = by * O - 2;      // staged-region origin
    int x0d = x0 - 1, y0d = y0 - 1;            // raw-input origin
    const float* im = img + (size_t)bb * PLANE;
    bool interior = (bx >= 1 && bx <= NTX - 2 && by >= 1 && by <= NTX - 2);
    int tid = threadIdx.x;

    // stage raw input 38x38
    if (interior) {
        for (int idx = tid; idx < RD * RD; idx += 256) {
            int r = idx / RD, c = idx - (idx / RD) * RD;
            sI[r * SD + c] = im[(y0d + r) * WW + (x0d + c)];
        }
    } else {
        for (int idx = tid; idx < RD * RD; idx += 256) {
            int r = idx / RD, c = idx - (idx / RD) * RD;
            int gy = clampi(y0d + r, 0, HH - 1), gx = clampi(x0d + c, 0, WW - 1);
            sI[r * SD + c] = im[gy * WW + gx];
        }
    }
    __syncthreads();

    // demosaick 36x36 -> sdR, sdB, sG
    if (interior) {
        for (int idx = tid; idx < R2 * R2; idx += 256) {
            int r = idx / R2, c = idx - (idx / R2) * R2;
            int rI = r + 1, cI = c + 1;
            float accR = 0.f, accG = 0.f, accB = 0.f;
#pragma unroll
            for (int dy = -1; dy <= 1; ++dy) {
#pragma unroll
                for (int dx = -1; dx <= 1; ++dx) {
                    float v = sI[(rI + dy) * SD + (cI + dx)];
                    // y0,x0 even -> global parity == region parity
                    demo_acc(v, (r + dy) & 1, (c + dx) & 1,
                             dy < 0 ? -dy : dy, dx < 0 ? -dx : dx, accR, accG, accB);
                }
            }
            sG[r * S2 + c] = accG;
            sdR[r * S2 + c] = accR - accG;
            sdB[r * S2 + c] = accB - accG;
        }
    } else {
        for (int idx = tid; idx < R2 * R2; idx += 256) {
            int r = idx / R2, c = idx - (idx / R2) * R2;
            int gy = clampi(y0 + r, 0, HH - 1), gx = clampi(x0 + c, 0, WW - 1);
            float accR = 0.f, accG = 0.f, accB = 0.f;
#pragma unroll
            for (int dy = -1; dy <= 1; ++dy) {
#pragma unroll
                for (int dx = -1; dx <= 1; ++dx) {
                    int cy = clampi(gy + dy, 0, HH - 1);
                    int cx = clampi(gx + dx, 0, WW - 1);
                    float v = sI[(cy - y0d) * SD + (cx - x0d)];
                    demo_acc(v, cy & 1, cx & 1,
                             dy < 0 ? -dy : dy, dx < 0 ? -dx : dx, accR, accG, accB);
                }
            }
            sG[r * S2 + c] = accG;
            sdR[r * S2 + c] = accR - accG;
            sdB[r * S2 + c] = accB - accG;
        }
    }
    __syncthreads();

    phase1(sdR, sdB, uR, uB, tid, interior, y0, x0);
    __syncthreads();

    float* oR = dst + (size_t)bb * 3 * PLANE;
    float* oG = oR + PLANE;
    float* oB = oR + 2 * PLANE;
    phase2(sG, uR, uB, oR, oG, oB, tid, interior, y0, x0);
}

// ---------------- kernel B: one median iteration, staged in LDS ----------------
__global__ __launch_bounds__(256) void iter_kernel(const float* __restrict__ src,
                                                   float* __restrict__ dst) {
    __shared__ float smem[5 * R2 * S2];
    float* sdR = smem;
    float* sdB = sdR + R2 * S2;
    float* sG  = sdB + R2 * S2;
    float* uR  = sG + R2 * S2;
    float* uB  = uR + R2 * S2;

    int bx = blockIdx.x, by = blockIdx.y, bb = blockIdx.z;
    int x0 = bx * O - 2, y0 = by * O - 2;
    const float* Rp = src + (size_t)bb * 3 * PLANE;
    const float* Gp = Rp + PLANE;
    const float* Bp = Rp + 2 * PLANE;
    bool interior = (bx >= 1 && bx <= NTX - 2 && by >= 1 && by <= NTX - 2);
    int tid = threadIdx.x;

    // stage dR, dB, G on 36x36
    if (interior) {
        for (int idx = tid; idx < R2 * R2; idx += 256) {
            int r = idx / R2, c = idx - (idx / R2) * R2;
            int off = (y0 + r) * WW + (x0 + c);
            float rv = Rp[off], gv = Gp[off], bv = Bp[off];
            sdR[r * S2 + c] = rv - gv;
            sdB[r * S2 + c] = bv - gv;
            sG[r * S2 + c] = gv;
        }
    } else {
        for (int idx = tid; idx < R2 * R2; idx += 256) {
            int r = idx / R2, c = idx - (idx / R2) * R2;
            int gy = clampi(y0 + r, 0, HH - 1), gx = clampi(x0 + c, 0, WW - 1);
            int off = gy * WW + gx;
            float rv = Rp[off], gv = Gp[off], bv = Bp[off];
            sdR[r * S2 + c] = rv - gv;
            sdB[r * S2 + c] = bv - gv;
            sG[r * S2 + c] = gv;
        }
    }
    __syncthreads();

    phase1(sdR, sdB, uR, uB, tid, interior, y0, x0);
    __syncthreads();

    float* oR = dst + (size_t)bb * 3 * PLANE;
    float* oG = oR + PLANE;
    float* oB = oR + 2 * PLANE;
    phase2(sG, uR, uB, oR, oG, oB, tid, interior, y0, x0);
}

extern "C" void kernel_launch(void* const* d_in, const int* in_sizes, int n_in,
                              void* d_out, int out_size, void* d_ws, size_t ws_size,
                              hipStream_t stream) {
    const float* img = (const float*)d_in[0];
    float* out = (float*)d_out;
    float* ws = (float*)d_ws;

    dim3 block(256);
    dim3 grid(NTX, NTX, NB);

    // demosaick+iter1 -> out ; iter2 out->ws ; iter3 ws->out
    demo_iter1_kernel<<<grid, block, 0, stream>>>(img, out);
    iter_kernel<<<grid, block, 0, stream>>>(out, ws);
    iter_kernel<<<grid, block, 0, stream>>>(ws, out);
}

// Round 6
// 183.552 us; speedup vs baseline: 2.3569x; 1.2471x over previous
//
#include <hip/hip_runtime.h>

#define HH 1024
#define WW 1024
#define NB 8
constexpr int PLANE = HH * WW;

#define S   40   // LDS plane stride (floats / packed-half2s) - multiple of 4 for b128
#define O   32   // output tile
#define NTX 32   // 1024 / O

typedef _Float16 h2 __attribute__((ext_vector_type(2)));

__device__ __forceinline__ int clampi(int v, int lo, int hi) {
    return v < lo ? lo : (v > hi ? hi : v);
}

union U2H { unsigned u; h2 h; };
__device__ __forceinline__ h2 u2h(unsigned v) { U2H x; x.u = v; return x.h; }
__device__ __forceinline__ unsigned h2u(h2 h) { U2H x; x.h = h; return x.u; }
__device__ __forceinline__ unsigned packdiff(float a, float b) {
    h2 h;
    h.x = (_Float16)a;
    h.y = (_Float16)b;
    return h2u(h);
}

__device__ __forceinline__ void cswap2(h2& a, h2& b) {
    h2 lo = __builtin_elementwise_min(a, b);
    b = __builtin_elementwise_max(a, b);
    a = lo;
}

// rank 4 (0-indexed) of 8, elementwise on both fp16 lanes. Same pruned Batcher
// network as the f32 version validated in rounds 1-4.
__device__ __forceinline__ h2 med8p(h2 v0, h2 v1, h2 v2, h2 v3,
                                    h2 v4, h2 v5, h2 v6, h2 v7) {
    cswap2(v0, v1); cswap2(v2, v3); cswap2(v4, v5); cswap2(v6, v7);
    cswap2(v0, v2); cswap2(v1, v3); cswap2(v4, v6); cswap2(v5, v7);
    cswap2(v1, v2); cswap2(v5, v6);
    h2 p2 = __builtin_elementwise_min(v2, v6), p3 = __builtin_elementwise_min(v3, v7);
    h2 p4 = __builtin_elementwise_max(v0, v4), p5 = __builtin_elementwise_max(v1, v5);
    return __builtin_elementwise_max(__builtin_elementwise_min(p3, p5),
                                     __builtin_elementwise_max(p2, p4));
}

// rank 2 (0-indexed) of 4, elementwise both lanes.
__device__ __forceinline__ h2 med4p(h2 a, h2 b, h2 c, h2 d) {
    h2 ab_hi = __builtin_elementwise_max(a, b), ab_lo = __builtin_elementwise_min(a, b);
    h2 cd_hi = __builtin_elementwise_max(c, d), cd_lo = __builtin_elementwise_min(c, d);
    return __builtin_elementwise_max(__builtin_elementwise_min(ab_hi, cd_hi),
                                     __builtin_elementwise_max(ab_lo, cd_lo));
}

__device__ __forceinline__ void demo_acc(float v, int pyn, int pxn, int ady, int adx,
                                         float& accR, float& accG, float& accB) {
    bool isr = (pyn == 0) && (pxn == 1);
    bool isb = (pyn == 1) && (pxn == 0);
    float wrb = 0.25f * (float)((2 - ady) * (2 - adx));
    int man = ady + adx;
    float wg = (man == 0) ? 1.0f : ((man == 1) ? 0.25f : 0.0f);
    accR += isr ? wrb * v : 0.0f;
    accB += isb ? wrb * v : 0.0f;
    accG += (!isr && !isb) ? wg * v : 0.0f;
}

// ---- phase 1: uRB[r][c-1] = -med8(dRB 8-neighbors) packed, rows/cols 1..34 ----
__device__ __forceinline__ void phase1(const unsigned* __restrict__ sdRB,
                                       unsigned* __restrict__ uRB,
                                       int tid, bool interior, int y0, int x0) {
    if (interior) {
        // 34 rows x 9 groups of 4 px; u cols 35,36 of each row are
        // garbage-but-unused (their windows read unstaged LDS; never consumed).
        for (int t = tid; t < 34 * 9; t += 256) {
            int r = 1 + t / 9, k = t - (t / 9) * 9;
            int a = r * S + 4 * k;
            uint4 q0 = *reinterpret_cast<const uint4*>(&sdRB[a - S]);
            uint2 e0 = *reinterpret_cast<const uint2*>(&sdRB[a - S + 4]);
            uint4 q1 = *reinterpret_cast<const uint4*>(&sdRB[a]);
            uint2 e1 = *reinterpret_cast<const uint2*>(&sdRB[a + 4]);
            uint4 q2 = *reinterpret_cast<const uint4*>(&sdRB[a + S]);
            uint2 e2 = *reinterpret_cast<const uint2*>(&sdRB[a + S + 4]);
            unsigned w0[6] = {q0.x, q0.y, q0.z, q0.w, e0.x, e0.y};
            unsigned w1[6] = {q1.x, q1.y, q1.z, q1.w, e1.x, e1.y};
            unsigned w2[6] = {q2.x, q2.y, q2.z, q2.w, e2.x, e2.y};
            unsigned rr[4];
#pragma unroll
            for (int i = 0; i < 4; ++i) {
                h2 m = med8p(u2h(w0[i]), u2h(w0[i + 1]), u2h(w0[i + 2]),
                             u2h(w1[i]), u2h(w1[i + 2]),
                             u2h(w2[i]), u2h(w2[i + 1]), u2h(w2[i + 2]));
                rr[i] = h2u(-m);
            }
            *reinterpret_cast<uint4*>(&uRB[a]) = make_uint4(rr[0], rr[1], rr[2], rr[3]);
        }
    } else {
        for (int t = tid; t < 34 * 34; t += 256) {
            int r = 1 + t / 34, c = 1 + t - (t / 34) * 34;
            int gy = clampi(y0 + r, 0, HH - 1), gx = clampi(x0 + c, 0, WW - 1);
            int rm = clampi(gy - 1, 0, HH - 1) - y0, rp_ = clampi(gy + 1, 0, HH - 1) - y0;
            int cm = clampi(gx - 1, 0, WW - 1) - x0, cp = clampi(gx + 1, 0, WW - 1) - x0;
            h2 m = med8p(u2h(sdRB[rm * S + cm]), u2h(sdRB[rm * S + c]), u2h(sdRB[rm * S + cp]),
                         u2h(sdRB[r * S + cm]), u2h(sdRB[r * S + cp]),
                         u2h(sdRB[rp_ * S + cm]), u2h(sdRB[rp_ * S + c]), u2h(sdRB[rp_ * S + cp]));
            uRB[r * S + (c - 1)] = h2u(-m);
        }
    }
}

// ---- phase 2: Rn=G-uR, Bn=G-uB, Gn=0.5*(med4(uR)+med4(uB)+Rn+Bn) on 32x32 ----
__device__ __forceinline__ void phase2(const float* __restrict__ sG,
                                       const unsigned* __restrict__ uRB,
                                       float* __restrict__ oR, float* __restrict__ oG,
                                       float* __restrict__ oB,
                                       int tid, bool interior, int y0, int x0) {
    if (interior) {
        int r = 2 + (tid >> 3);
        int k = tid & 7;
        int c0 = 2 + 4 * k;
        int a = r * S + 4 * k;   // u window base (holds u cols 4k+1 .. 4k+6)
        uint4 qc = *reinterpret_cast<const uint4*>(&uRB[a]);
        uint2 ec = *reinterpret_cast<const uint2*>(&uRB[a + 4]);
        uint4 qu = *reinterpret_cast<const uint4*>(&uRB[a - S]);
        uint2 eu = *reinterpret_cast<const uint2*>(&uRB[a - S + 4]);
        uint4 qd = *reinterpret_cast<const uint4*>(&uRB[a + S]);
        uint2 ed = *reinterpret_cast<const uint2*>(&uRB[a + S + 4]);
        unsigned wc[6] = {qc.x, qc.y, qc.z, qc.w, ec.x, ec.y};
        unsigned wu[6] = {qu.x, qu.y, qu.z, qu.w, eu.x, eu.y};
        unsigned wd[6] = {qd.x, qd.y, qd.z, qd.w, ed.x, ed.y};
        float2 g01 = *reinterpret_cast<const float2*>(&sG[r * S + c0]);
        float2 g23 = *reinterpret_cast<const float2*>(&sG[r * S + c0 + 2]);
        float gg[4] = {g01.x, g01.y, g23.x, g23.y};
        float R4[4], G4[4], B4[4];
#pragma unroll
        for (int i = 0; i < 4; ++i) {
            h2 m = med4p(u2h(wu[1 + i]), u2h(wc[i]), u2h(wc[2 + i]), u2h(wd[1 + i]));
            h2 uc = u2h(wc[1 + i]);
            float Gc = gg[i];
            float Rn = Gc - (float)uc.x;
            float Bn = Gc - (float)uc.y;
            float Gn = 0.5f * ((float)m.x + (float)m.y + Rn + Bn);
            R4[i] = Rn; G4[i] = Gn; B4[i] = Bn;
        }
        int go = (y0 + r) * WW + (x0 + c0);
        *reinterpret_cast<float4*>(&oR[go]) = make_float4(R4[0], R4[1], R4[2], R4[3]);
        *reinterpret_cast<float4*>(&oG[go]) = make_float4(G4[0], G4[1], G4[2], G4[3]);
        *reinterpret_cast<float4*>(&oB[go]) = make_float4(B4[0], B4[1], B4[2], B4[3]);
    } else {
#pragma unroll
        for (int kk = 0; kk < 4; ++kk) {
            int idx = tid + kk * 256;
            int r = 2 + (idx >> 5), c = 2 + (idx & 31);
            int gy = y0 + r, gx = x0 + c;   // always in [0,1023]: tiles cover exactly
            int rm = clampi(gy - 1, 0, HH - 1) - y0, rp_ = clampi(gy + 1, 0, HH - 1) - y0;
            int cm = clampi(gx - 1, 0, WW - 1) - x0, cp = clampi(gx + 1, 0, WW - 1) - x0;
            h2 m = med4p(u2h(uRB[rm * S + (c - 1)]), u2h(uRB[r * S + (cm - 1)]),
                         u2h(uRB[r * S + (cp - 1)]), u2h(uRB[rp_ * S + (c - 1)]));
            h2 uc = u2h(uRB[r * S + (c - 1)]);
            float Gc = sG[r * S + c];
            float Rn = Gc - (float)uc.x;
            float Bn = Gc - (float)uc.y;
            float Gn = 0.5f * ((float)m.x + (float)m.y + Rn + Bn);
            int go = gy * WW + gx;
            oR[go] = Rn; oG[go] = Gn; oB[go] = Bn;
        }
    }
}

// ---------------- kernel A: demosaick (quad-specialized, in LDS) + iteration 1 ----------------
__global__ __launch_bounds__(256) void demo_iter1_kernel(const float* __restrict__ img,
                                                         float* __restrict__ dst) {
    __shared__ __align__(16) float smem[4400];
    float* sI = smem;                                              // 38*40 raw input
    float* sG = smem + 1520;                                       // 36*40 f32 G
    unsigned* sdRB = reinterpret_cast<unsigned*>(smem + 2960);     // 36*40 packed (dR,dB)
    unsigned* uRB = reinterpret_cast<unsigned*>(smem);             // aliases sI after demosaick

    int bx = blockIdx.x, by = blockIdx.y, bb = blockIdx.z;
    int x0 = bx * O - 2, y0 = by * O - 2;
    const float* im = img + (size_t)bb * PLANE;
    bool interior = (bx >= 1 && bx <= NTX - 2 && by >= 1 && by <= NTX - 2);
    int tid = threadIdx.x;

    // stage raw input: rows y0-1..y0+36, cols x0-2..x0+37 (float4-aligned origin)
    if (interior) {
        for (int t = tid; t < 38 * 10; t += 256) {
            int r = t / 10, k = t - (t / 10) * 10;
            int gidx = (y0 - 1 + r) * WW + (x0 - 2 + 4 * k);
            *reinterpret_cast<float4*>(&sI[r * S + 4 * k]) =
                *reinterpret_cast<const float4*>(&im[gidx]);
        }
    } else {
        for (int t = tid; t < 38 * 40; t += 256) {
            int r = t / 40, c = t - (t / 40) * 40;
            int gy = clampi(y0 - 1 + r, 0, HH - 1), gx = clampi(x0 - 2 + c, 0, WW - 1);
            sI[r * S + c] = im[gy * WW + gx];
        }
    }
    __syncthreads();

    // demosaick 36x36 region -> sG (f32), sdRB (packed fp16 diffs)
    if (interior) {
        // quad (2x2 Bayer cell) specialization; region (0,0) has even global parity
        for (int t = tid; t < 18 * 18; t += 256) {
            int qr = t / 18, qc = t - (t / 18) * 18;
            float w[4][4];
#pragma unroll
            for (int i = 0; i < 4; ++i)
#pragma unroll
                for (int j = 0; j < 4; ++j)
                    w[i][j] = sI[(2 * qr + i) * S + 2 * qc + 1 + j];
            // p00 = G site (even,even), p01 = R site, p10 = B site, p11 = G site
            float g00 = w[1][1];
            float r00 = 0.5f * (w[1][0] + w[1][2]);
            float b00 = 0.5f * (w[0][1] + w[2][1]);
            float r01 = w[1][2];
            float g01 = 0.25f * (w[0][2] + w[2][2] + w[1][1] + w[1][3]);
            float b01 = 0.25f * (w[0][1] + w[0][3] + w[2][1] + w[2][3]);
            float b10 = w[2][1];
            float g10 = 0.25f * (w[1][1] + w[3][1] + w[2][0] + w[2][2]);
            float r10 = 0.25f * (w[1][0] + w[1][2] + w[3][0] + w[3][2]);
            float g11 = w[2][2];
            float r11 = 0.5f * (w[1][2] + w[3][2]);
            float b11 = 0.5f * (w[2][1] + w[2][3]);
            int a0 = (2 * qr) * S + 2 * qc, a1 = a0 + S;
            *reinterpret_cast<float2*>(&sG[a0]) = make_float2(g00, g01);
            *reinterpret_cast<float2*>(&sG[a1]) = make_float2(g10, g11);
            *reinterpret_cast<uint2*>(&sdRB[a0]) =
                make_uint2(packdiff(r00 - g00, b00 - g00), packdiff(r01 - g01, b01 - g01));
            *reinterpret_cast<uint2*>(&sdRB[a1]) =
                make_uint2(packdiff(r10 - g10, b10 - g10), packdiff(r11 - g11, b11 - g11));
        }
    } else {
        for (int t = tid; t < 36 * 36; t += 256) {
            int r = t / 36, c = t - (t / 36) * 36;
            int gy = clampi(y0 + r, 0, HH - 1), gx = clampi(x0 + c, 0, WW - 1);
            float accR = 0.f, accG = 0.f, accB = 0.f;
#pragma unroll
            for (int dy = -1; dy <= 1; ++dy)
#pragma unroll
                for (int dx = -1; dx <= 1; ++dx) {
                    int cy = clampi(gy + dy, 0, HH - 1);
                    int cx = clampi(gx + dx, 0, WW - 1);
                    float v = sI[(cy - (y0 - 1)) * S + (cx - (x0 - 2))];
                    demo_acc(v, cy & 1, cx & 1, dy < 0 ? -dy : dy, dx < 0 ? -dx : dx,
                             accR, accG, accB);
                }
            sG[r * S + c] = accG;
            sdRB[r * S + c] = packdiff(accR - accG, accB - accG);
        }
    }
    __syncthreads();

    phase1(sdRB, uRB, tid, interior, y0, x0);
    __syncthreads();

    float* oR = dst + (size_t)bb * 3 * PLANE;
    float* oG = oR + PLANE;
    float* oB = oR + 2 * PLANE;
    phase2(sG, uRB, oR, oG, oB, tid, interior, y0, x0);
}

// ---------------- kernel B: one median iteration ----------------
__global__ __launch_bounds__(256) void iter_kernel(const float* __restrict__ src,
                                                   float* __restrict__ dst) {
    __shared__ __align__(16) float smem[4320];
    float* sG = smem;                                              // 36*40
    unsigned* sdRB = reinterpret_cast<unsigned*>(smem + 1440);
    unsigned* uRB = reinterpret_cast<unsigned*>(smem + 2880);

    int bx = blockIdx.x, by = blockIdx.y, bb = blockIdx.z;
    int x0 = bx * O - 2, y0 = by * O - 2;
    const float* Rp = src + (size_t)bb * 3 * PLANE;
    const float* Gp = Rp + PLANE;
    const float* Bp = Rp + 2 * PLANE;
    bool interior = (bx >= 1 && bx <= NTX - 2 && by >= 1 && by <= NTX - 2);
    int tid = threadIdx.x;

    if (interior) {
        for (int t = tid; t < 36 * 9; t += 256) {
            int r = t / 9, k = t - (t / 9) * 9;
            int gidx = (y0 + r) * WW + (x0 + 4 * k);
            float2 ra = *reinterpret_cast<const float2*>(&Rp[gidx]);
            float2 rb = *reinterpret_cast<const float2*>(&Rp[gidx + 2]);
            float2 ga = *reinterpret_cast<const float2*>(&Gp[gidx]);
            float2 gb = *reinterpret_cast<const float2*>(&Gp[gidx + 2]);
            float2 ba = *reinterpret_cast<const float2*>(&Bp[gidx]);
            float2 bb2 = *reinterpret_cast<const float2*>(&Bp[gidx + 2]);
            int a = r * S + 4 * k;
            *reinterpret_cast<float4*>(&sG[a]) = make_float4(ga.x, ga.y, gb.x, gb.y);
            *reinterpret_cast<uint4*>(&sdRB[a]) =
                make_uint4(packdiff(ra.x - ga.x, ba.x - ga.x),
                           packdiff(ra.y - ga.y, ba.y - ga.y),
                           packdiff(rb.x - gb.x, bb2.x - gb.x),
                           packdiff(rb.y - gb.y, bb2.y - gb.y));
        }
    } else {
        for (int t = tid; t < 36 * 36; t += 256) {
            int r = t / 36, c = t - (t / 36) * 36;
            int gy = clampi(y0 + r, 0, HH - 1), gx = clampi(x0 + c, 0, WW - 1);
            int off = gy * WW + gx;
            float rv = Rp[off], gv = Gp[off], bv = Bp[off];
            sG[r * S + c] = gv;
            sdRB[r * S + c] = packdiff(rv - gv, bv - gv);
        }
    }
    __syncthreads();

    phase1(sdRB, uRB, tid, interior, y0, x0);
    __syncthreads();

    float* oR = dst + (size_t)bb * 3 * PLANE;
    float* oG = oR + PLANE;
    float* oB = oR + 2 * PLANE;
    phase2(sG, uRB, oR, oG, oB, tid, interior, y0, x0);
}

extern "C" void kernel_launch(void* const* d_in, const int* in_sizes, int n_in,
                              void* d_out, int out_size, void* d_ws, size_t ws_size,
                              hipStream_t stream) {
    const float* img = (const float*)d_in[0];
    float* out = (float*)d_out;
    float* ws = (float*)d_ws;

    dim3 block(256);
    dim3 grid(NTX, NTX, NB);

    // demosaick+iter1 -> out ; iter2 out->ws ; iter3 ws->out
    demo_iter1_kernel<<<grid, block, 0, stream>>>(img, out);
    iter_kernel<<<grid, block, 0, stream>>>(out, ws);
    iter_kernel<<<grid, block, 0, stream>>>(ws, out);
}

// Round 8
// 148.690 us; speedup vs baseline: 2.9094x; 1.2345x over previous
//
#include <hip/hip_runtime.h>

#define HH 1024
#define WW 1024
#define NB 8
constexpr int PLANE = HH * WW;

#define S   48   // LDS plane stride (u32/f32 units), multiple of 4
#define RG  46   // staged region rows
#define NTX 32   // tiles per dim (1024/32)

typedef _Float16 h2 __attribute__((ext_vector_type(2)));

__device__ __forceinline__ int clampi(int v, int lo, int hi) {
    return v < lo ? lo : (v > hi ? hi : v);
}

union U2H { unsigned u; h2 h; };
__device__ __forceinline__ h2 u2h(unsigned v) { U2H x; x.u = v; return x.h; }
__device__ __forceinline__ unsigned h2u(h2 h) { U2H x; x.h = h; return x.u; }
__device__ __forceinline__ unsigned packdiff(float a, float b) {
    h2 h; h.x = (_Float16)a; h.y = (_Float16)b; return h2u(h);
}

__device__ __forceinline__ void cswap2(h2& a, h2& b) {
    h2 lo = __builtin_elementwise_min(a, b);
    b = __builtin_elementwise_max(a, b);
    a = lo;
}

// rank 4 (0-indexed) of 8, both fp16 lanes. Pruned Batcher network (validated r1-r6).
__device__ __forceinline__ h2 med8p(h2 v0, h2 v1, h2 v2, h2 v3,
                                    h2 v4, h2 v5, h2 v6, h2 v7) {
    cswap2(v0, v1); cswap2(v2, v3); cswap2(v4, v5); cswap2(v6, v7);
    cswap2(v0, v2); cswap2(v1, v3); cswap2(v4, v6); cswap2(v5, v7);
    cswap2(v1, v2); cswap2(v5, v6);
    h2 p2 = __builtin_elementwise_min(v2, v6), p3 = __builtin_elementwise_min(v3, v7);
    h2 p4 = __builtin_elementwise_max(v0, v4), p5 = __builtin_elementwise_max(v1, v5);
    return __builtin_elementwise_max(__builtin_elementwise_min(p3, p5),
                                     __builtin_elementwise_max(p2, p4));
}

// rank 2 (0-indexed) of 4, both lanes.
__device__ __forceinline__ h2 med4p(h2 a, h2 b, h2 c, h2 d) {
    h2 ab_hi = __builtin_elementwise_max(a, b), ab_lo = __builtin_elementwise_min(a, b);
    h2 cd_hi = __builtin_elementwise_max(c, d), cd_lo = __builtin_elementwise_min(c, d);
    return __builtin_elementwise_max(__builtin_elementwise_min(ab_hi, cd_hi),
                                     __builtin_elementwise_max(ab_lo, cd_lo));
}

__device__ __forceinline__ void demo_acc(float v, int pyn, int pxn, int ady, int adx,
                                         float& accR, float& accG, float& accB) {
    bool isr = (pyn == 0) && (pxn == 1);
    bool isb = (pyn == 1) && (pxn == 0);
    float wrb = 0.25f * (float)((2 - ady) * (2 - adx));
    int man = ady + adx;
    float wg = (man == 0) ? 1.0f : ((man == 1) ? 0.25f : 0.0f);
    accR += isr ? wrb * v : 0.0f;
    accB += isb ? wrb * v : 0.0f;
    accG += (!isr && !isb) ? wg * v : 0.0f;
}

// ---------- vector LDS access helpers (CA = c0 & 3, 0 or 2) ----------
template <int CA>
__device__ __forceinline__ void load4u(const unsigned* row, int c0, unsigned w[4]) {
    if constexpr (CA == 0) {
        uint4 q = *reinterpret_cast<const uint4*>(row + c0);
        w[0] = q.x; w[1] = q.y; w[2] = q.z; w[3] = q.w;
    } else {
        uint2 a = *reinterpret_cast<const uint2*>(row + c0);
        uint2 b = *reinterpret_cast<const uint2*>(row + c0 + 2);
        w[0] = a.x; w[1] = a.y; w[2] = b.x; w[3] = b.y;
    }
}
// w[j] = row[c0-1+j], j<6
template <int CA>
__device__ __forceinline__ void load6u(const unsigned* row, int c0, unsigned w[6]) {
    if constexpr (CA == 0) {
        uint4 q = *reinterpret_cast<const uint4*>(row + c0);
        w[0] = row[c0 - 1];
        w[1] = q.x; w[2] = q.y; w[3] = q.z; w[4] = q.w;
        w[5] = row[c0 + 4];
    } else {
        uint4 a = *reinterpret_cast<const uint4*>(row + c0 - 2);
        uint4 b = *reinterpret_cast<const uint4*>(row + c0 + 2);
        w[0] = a.y; w[1] = a.z; w[2] = a.w; w[3] = b.x; w[4] = b.y; w[5] = b.z;
    }
}
template <int CA>
__device__ __forceinline__ void load4f(const float* row, int c0, float w[4]) {
    if constexpr (CA == 0) {
        float4 q = *reinterpret_cast<const float4*>(row + c0);
        w[0] = q.x; w[1] = q.y; w[2] = q.z; w[3] = q.w;
    } else {
        float2 a = *reinterpret_cast<const float2*>(row + c0);
        float2 b = *reinterpret_cast<const float2*>(row + c0 + 2);
        w[0] = a.x; w[1] = a.y; w[2] = b.x; w[3] = b.y;
    }
}
template <int CA>
__device__ __forceinline__ void store4f(float* row, int c0, const float v[4]) {
    if constexpr (CA == 0) {
        *reinterpret_cast<float4*>(row + c0) = make_float4(v[0], v[1], v[2], v[3]);
    } else {
        *reinterpret_cast<float2*>(row + c0) = make_float2(v[0], v[1]);
        *reinterpret_cast<float2*>(row + c0 + 2) = make_float2(v[2], v[3]);
    }
}
template <int CA>
__device__ __forceinline__ void store4u(unsigned* row, int c0, const unsigned v[4]) {
    if constexpr (CA == 0) {
        *reinterpret_cast<uint4*>(row + c0) = make_uint4(v[0], v[1], v[2], v[3]);
    } else {
        *reinterpret_cast<uint2*>(row + c0) = make_uint2(v[0], v[1]);
        *reinterpret_cast<uint2*>(row + c0 + 2) = make_uint2(v[2], v[3]);
    }
}

// ---------- interior phase 1: u = -med8(diffs), 2 rows x 4 cols per thread ----------
// u rows [R0, R0+2*NRP), cols [C0, C0+4*NG). SH = (C0-1)&3.
template <int R0, int NRP, int C0, int NG, int SH>
__device__ __forceinline__ void p1_int(const unsigned* __restrict__ sdRB,
                                       unsigned* __restrict__ uRB, int tid) {
    if (tid < NRP * NG) {
        int rp = tid / NG, g = tid - rp * NG;
        int r0 = R0 + 2 * rp;
        int B = (C0 - 1 - SH) + 4 * g;   // aligned
        unsigned w[4][6];
#pragma unroll
        for (int i = 0; i < 4; ++i) {
            const unsigned* row = &sdRB[(r0 - 1 + i) * S + B];
            uint4 q0 = *reinterpret_cast<const uint4*>(row);
            uint4 q1 = *reinterpret_cast<const uint4*>(row + 4);
            unsigned e[8] = {q0.x, q0.y, q0.z, q0.w, q1.x, q1.y, q1.z, q1.w};
#pragma unroll
            for (int j = 0; j < 6; ++j) w[i][j] = e[SH + j];
        }
        int c0 = C0 + 4 * g;
#pragma unroll
        for (int rr = 0; rr < 2; ++rr) {
#pragma unroll
            for (int i = 0; i < 4; ++i) {
                h2 m = med8p(u2h(w[rr][i]), u2h(w[rr][i + 1]), u2h(w[rr][i + 2]),
                             u2h(w[rr + 1][i]), u2h(w[rr + 1][i + 2]),
                             u2h(w[rr + 2][i]), u2h(w[rr + 2][i + 1]), u2h(w[rr + 2][i + 2]));
                uRB[(r0 + rr) * S + c0 + i] = h2u(-m);
            }
        }
    }
}

// ---------- interior phase 2: Rn,Bn,Gn on 2x4 px per thread ----------
template <int R0, int NRP, int C0, int NG, int CA, bool FINAL>
__device__ __forceinline__ void p2_int(float* __restrict__ sG, unsigned* __restrict__ sdRB,
                                       const unsigned* __restrict__ uRB, int tid,
                                       int y0, int x0,
                                       float* __restrict__ oR, float* __restrict__ oG,
                                       float* __restrict__ oB) {
    if (tid < NRP * NG) {
        int rp = tid / NG, g = tid - rp * NG;
        int r0 = R0 + 2 * rp;
        int c0 = C0 + 4 * g;
        unsigned wm[4], wp[4], w0[6], w1[6];
        load4u<CA>(&uRB[(r0 - 1) * S], c0, wm);
        load6u<CA>(&uRB[(r0) * S], c0, w0);
        load6u<CA>(&uRB[(r0 + 1) * S], c0, w1);
        load4u<CA>(&uRB[(r0 + 2) * S], c0, wp);
        float g0[4], g1[4];
        load4f<CA>(&sG[r0 * S], c0, g0);
        load4f<CA>(&sG[(r0 + 1) * S], c0, g1);
        float Rv[2][4], Gv[2][4], Bv[2][4];
#pragma unroll
        for (int i = 0; i < 4; ++i) {
            {   // row r0
                h2 m = med4p(u2h(wm[i]), u2h(w0[i]), u2h(w0[i + 2]), u2h(w1[i + 1]));
                h2 uc = u2h(w0[i + 1]);
                float Gc = g0[i];
                float Rn = Gc - (float)uc.x, Bn = Gc - (float)uc.y;
                float Gn = 0.5f * ((float)m.x + (float)m.y + Rn + Bn);
                Rv[0][i] = Rn; Gv[0][i] = Gn; Bv[0][i] = Bn;
            }
            {   // row r0+1
                h2 m = med4p(u2h(w0[i + 1]), u2h(w1[i]), u2h(w1[i + 2]), u2h(wp[i]));
                h2 uc = u2h(w1[i + 1]);
                float Gc = g1[i];
                float Rn = Gc - (float)uc.x, Bn = Gc - (float)uc.y;
                float Gn = 0.5f * ((float)m.x + (float)m.y + Rn + Bn);
                Rv[1][i] = Rn; Gv[1][i] = Gn; Bv[1][i] = Bn;
            }
        }
        if constexpr (FINAL) {
#pragma unroll
            for (int rr = 0; rr < 2; ++rr) {
                size_t o = (size_t)(y0 + r0 + rr) * WW + (x0 + c0);
                *reinterpret_cast<float4*>(&oR[o]) = make_float4(Rv[rr][0], Rv[rr][1], Rv[rr][2], Rv[rr][3]);
                *reinterpret_cast<float4*>(&oG[o]) = make_float4(Gv[rr][0], Gv[rr][1], Gv[rr][2], Gv[rr][3]);
                *reinterpret_cast<float4*>(&oB[o]) = make_float4(Bv[rr][0], Bv[rr][1], Bv[rr][2], Bv[rr][3]);
            }
        } else {
#pragma unroll
            for (int rr = 0; rr < 2; ++rr) {
                unsigned pd[4];
#pragma unroll
                for (int i = 0; i < 4; ++i)
                    pd[i] = packdiff(Rv[rr][i] - Gv[rr][i], Bv[rr][i] - Gv[rr][i]);
                store4f<CA>(&sG[(r0 + rr) * S], c0, Gv[rr]);
                store4u<CA>(&sdRB[(r0 + rr) * S], c0, pd);
            }
        }
    }
}

// ---------- border (clamped, scalar) phase helpers ----------
__device__ void p1_b(const unsigned* sdRB, unsigned* uRB, int tid,
                     int y0, int x0, int rlo, int nr, int clo, int nc) {
    for (int t = tid; t < nr * nc; t += 256) {
        int r = rlo + t / nc, c = clo + t - (t / nc) * nc;
        int gy = clampi(y0 + r, 0, HH - 1), gx = clampi(x0 + c, 0, WW - 1);
        int rm = clampi(gy - 1, 0, HH - 1) - y0, rp = clampi(gy + 1, 0, HH - 1) - y0;
        int cm = clampi(gx - 1, 0, WW - 1) - x0, cp = clampi(gx + 1, 0, WW - 1) - x0;
        h2 m = med8p(u2h(sdRB[rm * S + cm]), u2h(sdRB[rm * S + c]), u2h(sdRB[rm * S + cp]),
                     u2h(sdRB[r * S + cm]), u2h(sdRB[r * S + cp]),
                     u2h(sdRB[rp * S + cm]), u2h(sdRB[rp * S + c]), u2h(sdRB[rp * S + cp]));
        uRB[r * S + c] = h2u(-m);
    }
}

__device__ void p2_b(float* sG, unsigned* sdRB, const unsigned* uRB, int tid,
                     int y0, int x0, int rlo, int nr, int clo, int nc, bool fin,
                     float* oR, float* oG, float* oB) {
    for (int t = tid; t < nr * nc; t += 256) {
        int r = rlo + t / nc, c = clo + t - (t / nc) * nc;
        int gy = clampi(y0 + r, 0, HH - 1), gx = clampi(x0 + c, 0, WW - 1);
        int rm = clampi(gy - 1, 0, HH - 1) - y0, rp = clampi(gy + 1, 0, HH - 1) - y0;
        int cm = clampi(gx - 1, 0, WW - 1) - x0, cp = clampi(gx + 1, 0, WW - 1) - x0;
        h2 m = med4p(u2h(uRB[rm * S + c]), u2h(uRB[r * S + cm]),
                     u2h(uRB[r * S + cp]), u2h(uRB[rp * S + c]));
        h2 uc = u2h(uRB[r * S + c]);
        float Gc = sG[r * S + c];
        float Rn = Gc - (float)uc.x, Bn = Gc - (float)uc.y;
        float Gn = 0.5f * ((float)m.x + (float)m.y + Rn + Bn);
        if (fin) {
            size_t o = (size_t)(y0 + r) * WW + (x0 + c);   // exact, in-range
            oR[o] = Rn; oG[o] = Gn; oB[o] = Bn;
        } else {
            sG[r * S + c] = Gn;
            sdRB[r * S + c] = packdiff(Rn - Gn, Bn - Gn);
        }
    }
}

// ---------- the fused kernel ----------
__global__ __launch_bounds__(256, 4) void fused_kernel(const float* __restrict__ img,
                                                       float* __restrict__ dst) {
    __shared__ __align__(16) unsigned smem[3 * RG * S];
    float* sI = reinterpret_cast<float*>(smem);          // raw input; later aliased by uRB
    unsigned* uRB = smem;
    unsigned* sdRB = smem + RG * S;
    float* sG = reinterpret_cast<float*>(smem + 2 * RG * S);

    int bx = blockIdx.x, by = blockIdx.y, bb = blockIdx.z;
    int x0 = bx * 32 - 8, y0 = by * 32 - 7;              // staged-region origin
    const float* im = img + (size_t)bb * PLANE;
    float* oR = dst + (size_t)bb * 3 * PLANE;
    float* oG = oR + PLANE;
    float* oB = oR + 2 * PLANE;
    int tid = threadIdx.x;
    bool interior = (bx >= 1 && bx <= 30 && by >= 1 && by <= 30);

    if (interior) {
        // ---- stage raw 46x48 (float4) ----
        for (int t = tid; t < RG * 12; t += 256) {
            int r = t / 12, k = t - (t / 12) * 12;
            *reinterpret_cast<float4*>(&sI[r * S + 4 * k]) =
                *reinterpret_cast<const float4*>(&im[(size_t)(y0 + r) * WW + x0 + 4 * k]);
        }
        __syncthreads();
        // ---- demosaick: 22 quad-rows x 11 quad-pair-cols, 2x4 px per thread ----
        // NO barrier inside this divergent region (round-7 bug): demosaick reads
        // sI and writes only sG/sdRB — disjoint LDS; uRB (aliasing sI) is first
        // written in p1, after the top-level barrier below.
        if (tid < 242) {
            int qi = tid / 11, g = tid - (tid / 11) * 11;
            int rA = 1 + 2 * qi;          // anchor row; global gy even
            int B = 4 * g;                // w[i][j] = sI[(rA-1+i)*S + B+1+j]
            float w[4][6];
#pragma unroll
            for (int i = 0; i < 4; ++i) {
                const float* row = &sI[(rA - 1 + i) * S + B];
                float4 a = *reinterpret_cast<const float4*>(row);
                float4 b = *reinterpret_cast<const float4*>(row + 4);
                w[i][0] = a.y; w[i][1] = a.z; w[i][2] = a.w;
                w[i][3] = b.x; w[i][4] = b.y; w[i][5] = b.z;
            }
#pragma unroll
            for (int q = 0; q < 2; ++q) {
                int jb = 1 + 2 * q;
                float g00 = w[1][jb];
                float r00 = 0.5f * (w[1][jb - 1] + w[1][jb + 1]);
                float b00 = 0.5f * (w[0][jb] + w[2][jb]);
                float r01 = w[1][jb + 1];
                float g01 = 0.25f * (w[0][jb + 1] + w[2][jb + 1] + w[1][jb] + w[1][jb + 2]);
                float b01 = 0.25f * (w[0][jb] + w[0][jb + 2] + w[2][jb] + w[2][jb + 2]);
                float b10 = w[2][jb];
                float g10 = 0.25f * (w[1][jb] + w[3][jb] + w[2][jb - 1] + w[2][jb + 1]);
                float r10 = 0.25f * (w[1][jb - 1] + w[1][jb + 1] + w[3][jb - 1] + w[3][jb + 1]);
                float g11 = w[2][jb + 1];
                float r11 = 0.5f * (w[1][jb + 1] + w[3][jb + 1]);
                float b11 = 0.5f * (w[2][jb] + w[2][jb + 2]);
                int a0 = rA * S + 2 + 4 * g + 2 * q;
                *reinterpret_cast<float2*>(&sG[a0]) = make_float2(g00, g01);
                *reinterpret_cast<float2*>(&sG[a0 + S]) = make_float2(g10, g11);
                *reinterpret_cast<uint2*>(&sdRB[a0]) =
                    make_uint2(packdiff(r00 - g00, b00 - g00), packdiff(r01 - g01, b01 - g01));
                *reinterpret_cast<uint2*>(&sdRB[a0 + S]) =
                    make_uint2(packdiff(r10 - g10, b10 - g10), packdiff(r11 - g11, b11 - g11));
            }
        }
        __syncthreads();
        // ---- iteration 1 ----
        p1_int<2, 21, 3, 11, 2>(sdRB, uRB, tid);
        __syncthreads();
        p2_int<3, 20, 4, 10, 0, false>(sG, sdRB, uRB, tid, y0, x0, oR, oG, oB);
        __syncthreads();
        // ---- iteration 2 ----
        p1_int<4, 19, 5, 10, 0>(sdRB, uRB, tid);
        __syncthreads();
        p2_int<5, 18, 6, 9, 2, false>(sG, sdRB, uRB, tid, y0, x0, oR, oG, oB);
        __syncthreads();
        // ---- iteration 3 (final -> global) ----
        p1_int<6, 17, 7, 9, 2>(sdRB, uRB, tid);
        __syncthreads();
        p2_int<7, 16, 8, 8, 0, true>(sG, sdRB, uRB, tid, y0, x0, oR, oG, oB);
    } else {
        // ---- border: clamped scalar phases ----
        for (int t = tid; t < RG * S; t += 256) {
            int r = t / S, c = t - (t / S) * S;
            int gy = clampi(y0 + r, 0, HH - 1), gx = clampi(x0 + c, 0, WW - 1);
            sI[r * S + c] = im[(size_t)gy * WW + gx];
        }
        __syncthreads();
        {
            // demosaick on rows [1,45) x cols [2,46), values at clamped coords.
            for (int t = tid; t < 44 * 44; t += 256) {
                int r = 1 + t / 44, c = 2 + t - (t / 44) * 44;
                int gy = clampi(y0 + r, 0, HH - 1), gx = clampi(x0 + c, 0, WW - 1);
                float accR = 0.f, accG = 0.f, accB = 0.f;
#pragma unroll
                for (int dy = -1; dy <= 1; ++dy)
#pragma unroll
                    for (int dx = -1; dx <= 1; ++dx) {
                        int cy = clampi(gy + dy, 0, HH - 1);
                        int cx = clampi(gx + dx, 0, WW - 1);
                        float v = sI[(cy - y0) * S + (cx - x0)];
                        demo_acc(v, cy & 1, cx & 1, dy < 0 ? -dy : dy, dx < 0 ? -dx : dx,
                                 accR, accG, accB);
                    }
                sG[r * S + c] = accG;
                sdRB[r * S + c] = packdiff(accR - accG, accB - accG);
            }
        }
        __syncthreads();
        p1_b(sdRB, uRB, tid, y0, x0, 2, 42, 3, 42);
        __syncthreads();
        p2_b(sG, sdRB, uRB, tid, y0, x0, 3, 40, 4, 40, false, oR, oG, oB);
        __syncthreads();
        p1_b(sdRB, uRB, tid, y0, x0, 4, 38, 5, 38);
        __syncthreads();
        p2_b(sG, sdRB, uRB, tid, y0, x0, 5, 36, 6, 36, false, oR, oG, oB);
        __syncthreads();
        p1_b(sdRB, uRB, tid, y0, x0, 6, 34, 7, 34);
        __syncthreads();
        p2_b(sG, sdRB, uRB, tid, y0, x0, 7, 32, 8, 32, true, oR, oG, oB);
    }
}

extern "C" void kernel_launch(void* const* d_in, const int* in_sizes, int n_in,
                              void* d_out, int out_size, void* d_ws, size_t ws_size,
                              hipStream_t stream) {
    const float* img = (const float*)d_in[0];
    float* out = (float*)d_out;
    dim3 block(256);
    dim3 grid(NTX, NTX, NB);
    fused_kernel<<<grid, block, 0, stream>>>(img, out);
}